// Round 9
// baseline (437.289 us; speedup 1.0000x reference)
//
#include <hip/hip_runtime.h>

#define NB    256               // batch
#define NT    512               // time steps
#define NF    33                // features incl. flag channel
#define BOND  64
#define NOUT  32
#define TC    64                // chunk length
#define NCH   (NT / TC)         // 8 chunks per batch

typedef _Float16 f16x4 __attribute__((ext_vector_type(4)));
typedef _Float16 f16x8 __attribute__((ext_vector_type(8)));
typedef float    f32x4 __attribute__((ext_vector_type(4)));

#define MFMA16(a, b, c) __builtin_amdgcn_mfma_f32_16x16x32_f16((a), (b), (c), 0, 0, 0)

// ---------------------------------------------------------------------------
// Phase 0: pack core channels f=1..32 into f16 MFMA A-fragment order,
// COLUMN-MAJOR flatten n' = j*64 + i (verbatim rounds 4-6, HW-verified).
// ---------------------------------------------------------------------------
__global__ __launch_bounds__(64) void pack_cfrag(const float* __restrict__ core,
                                                 _Float16* __restrict__ cfrag)
{
    int tid = blockIdx.x * 64 + threadIdx.x;      // 0 .. 16383
    int nt = tid >> 6, l = tid & 63;
    int g = l >> 4, c = l & 15;
    int n = nt * 16 + c;
    int i = n & 63, j = n >> 6;                   // column-major flatten
    const float* src = core + (size_t)i * (NF * BOND) + (size_t)(1 + g * 8) * BOND + j;
    f16x8 v;
    #pragma unroll
    for (int m = 0; m < 8; ++m) v[m] = (_Float16)src[(size_t)m * BOND];
    *(f16x8*)(cfrag + (size_t)tid * 8) = v;
}

// ---------------------------------------------------------------------------
// Phase 1: wave-specialized (round-8 structure, bit-verified; spill fixed by
// launch_bounds(512,1) -> 256-VGPR budget, no scratch).
// Waves 0-3: chain, P rows 16w..16w+15 in regs, per-step self-stage.
// Waves 4-7: form next round's 8 M^T slices into the other Mb half.
// M^T layout: slice sl, buffer-row j (M col), logical col i stored at
//   i ^ ((j&7)<<3) ^ (sl<<3)   (row-key XOR + slice-key XOR, stride 4096 f16).
// Barriers: stage-sync + 8 matched round events.
// ---------------------------------------------------------------------------
__global__ __launch_bounds__(512, 1) void chunk_prod(const float* __restrict__ x,
                                                     const _Float16* __restrict__ cfrag,
                                                     float* __restrict__ Pout)
{
    __shared__ __align__(16) _Float16 Mb[2][8 * 4096];   // dbuf x 8 slices
    __shared__ __align__(16) _Float16 Pst[4][16 * 64];   // per-chain-wave stage
    __shared__ __align__(16) _Float16 Xl[TC * 32];
    __shared__ float x0l[TC];

    const int tid = (int)threadIdx.x;
    const int l = tid & 63, w = tid >> 6;         // 8 waves
    const int g = l >> 4, c = l & 15;
    const int ch = (int)blockIdx.x, b = (int)blockIdx.y;
    const int sw = (c & 7) << 3;

    // ---- stage x chunk ----
    const float* xb = x + (size_t)b * (NT * NF) + (size_t)(ch * TC) * NF;
    for (int idx = tid; idx < TC * NF; idx += 512) {
        int t = idx / NF, f = idx - t * NF;
        float v = xb[idx];
        if (f == 0) x0l[t] = v;
        else        Xl[t * 32 + (f - 1)] = (_Float16)v;
    }
    __syncthreads();                              // event 0

    if (w >= 4) {
        // ================= formation waves =================
        const int fw = w - 4;                     // 0..3, owns n-tiles fw*64..+63
        const int sl = c & 7, sx = sl << 3;       // slice = c&7 (cols c, c+8 dup)
        const _Float16* cf0 = cfrag + ((size_t)(fw * 64) * 64 + (size_t)l) * 8;
        f16x8 creg[32];                           // cache half the tiles in regs
        #pragma unroll
        for (int q = 0; q < 32; ++q) creg[q] = *(const f16x8*)(cf0 + (size_t)q * 512);

        #pragma unroll 1
        for (int gi = 0; gi < 8; ++gi) {          // group gi ready before round gi
            _Float16* Mg = Mb[gi & 1];
            f16x8 xa = *(const f16x8*)(Xl + (gi * 8 + sl) * 32 + 8 * g);
            float x0v = x0l[gi * 8 + sl];
            #pragma unroll
            for (int q = 0; q < 64; ++q) {
                int nt = fw * 64 + q;
                f16x8 ca = (q < 32) ? creg[q] : *(const f16x8*)(cf0 + (size_t)q * 512);
                f32x4 z = {0.f, 0.f, 0.f, 0.f};
                f32x4 d = MFMA16(ca, xa, z);      // lane: M[i0..i0+3][j], slice sl
                int j  = nt >> 2;
                int i0 = ((nt & 3) << 4) + (g << 2);
                int dr = j - i0;                  // diag slot if 0..3
                f16x4 mv;
                mv[0] = (_Float16)((dr == 0) ? d[0] + x0v : d[0]);   // RNE
                mv[1] = (_Float16)((dr == 1) ? d[1] + x0v : d[1]);
                mv[2] = (_Float16)((dr == 2) ? d[2] + x0v : d[2]);
                mv[3] = (_Float16)((dr == 3) ? d[3] + x0v : d[3]);
                *(f16x4*)(&Mg[sl * 4096 + (j << 6) + (i0 ^ ((j & 7) << 3) ^ sx)]) = mv;
            }
            __syncthreads();                      // events 1..8
        }
    } else {
        // ================= chain waves =================
        _Float16* Pw = &Pst[w][0];                // private 16x64 stage
        f16x8 a0, a1;                             // P[16w+c][kh*32+8g+m]
        #pragma unroll
        for (int m = 0; m < 8; ++m) {             // P = I (exact in f16)
            a0[m] = (_Float16)(((16 * w + c) == (8 * g + m)) ? 1.f : 0.f);
            a1[m] = (_Float16)(((16 * w + c) == (32 + 8 * g + m)) ? 1.f : 0.f);
        }
        f32x4 q0, q1, q2, q3;
        #pragma unroll 1
        for (int r = 0; r < 8; ++r) {
            __syncthreads();                      // events 1..8 (round r gated)
            const _Float16* Mg = Mb[r & 1];
            #pragma unroll
            for (int s = 0; s < 8; ++s) {
                const _Float16* Ms = Mg + s * 4096;
                const int kx0 = (8 * g) ^ sw ^ (s << 3);
                const int kx1 = kx0 ^ 32;
                f16x8 b00 = *(const f16x8*)(Ms + (c)      * 64 + kx0);
                f16x8 b01 = *(const f16x8*)(Ms + (c)      * 64 + kx1);
                f16x8 b10 = *(const f16x8*)(Ms + (16 + c) * 64 + kx0);
                f16x8 b11 = *(const f16x8*)(Ms + (16 + c) * 64 + kx1);
                f16x8 b20 = *(const f16x8*)(Ms + (32 + c) * 64 + kx0);
                f16x8 b21 = *(const f16x8*)(Ms + (32 + c) * 64 + kx1);
                f16x8 b30 = *(const f16x8*)(Ms + (48 + c) * 64 + kx0);
                f16x8 b31 = *(const f16x8*)(Ms + (48 + c) * 64 + kx1);
                f32x4 z = {0.f, 0.f, 0.f, 0.f};
                // swapped slots (round-6 verified): lane holds P'[16w+c][jb*16+4g+e]
                q0 = MFMA16(b00, a0, z); q0 = MFMA16(b01, a1, q0);
                q1 = MFMA16(b10, a0, z); q1 = MFMA16(b11, a1, q1);
                q2 = MFMA16(b20, a0, z); q2 = MFMA16(b21, a1, q2);
                q3 = MFMA16(b30, a0, z); q3 = MFMA16(b31, a1, q3);
                if (!(r == 7 && s == 7)) {
                    f16x4 h0, h1, h2, h3;         // RNE, as round 6
                    h0[0]=(_Float16)q0[0]; h0[1]=(_Float16)q0[1]; h0[2]=(_Float16)q0[2]; h0[3]=(_Float16)q0[3];
                    h1[0]=(_Float16)q1[0]; h1[1]=(_Float16)q1[1]; h1[2]=(_Float16)q1[2]; h1[3]=(_Float16)q1[3];
                    h2[0]=(_Float16)q2[0]; h2[1]=(_Float16)q2[1]; h2[2]=(_Float16)q2[2]; h2[3]=(_Float16)q2[3];
                    h3[0]=(_Float16)q3[0]; h3[1]=(_Float16)q3[1]; h3[2]=(_Float16)q3[2]; h3[3]=(_Float16)q3[3];
                    const int wc = (4 * g) ^ sw;  // row-key XOR store (row = c)
                    *(f16x4*)(Pw + c * 64 + wc)        = h0;
                    *(f16x4*)(Pw + c * 64 + (wc ^ 16)) = h1;
                    *(f16x4*)(Pw + c * 64 + (wc ^ 32)) = h2;
                    *(f16x4*)(Pw + c * 64 + (wc ^ 48)) = h3;
                    a0 = *(const f16x8*)(Pw + c * 64 + ((8 * g) ^ sw));
                    a1 = *(const f16x8*)(Pw + c * 64 + ((32 + 8 * g) ^ sw));
                }
            }
        }
        // final chunk product in f32 (pre-rounding), rows 16w+c
        float* Po = Pout + (size_t)(b * NCH + ch) * 4096;
        const int prow = 16 * w + c;
        *(f32x4*)(Po + prow * 64 +  0 + 4 * g) = q0;
        *(f32x4*)(Po + prow * 64 + 16 + 4 * g) = q1;
        *(f32x4*)(Po + prow * 64 + 32 + 4 * g) = q2;
        *(f32x4*)(Po + prow * 64 + 48 + 4 * g) = q3;
    }
}

// ---------------------------------------------------------------------------
// Phase 2: per batch, v = alpha; v = v @ P_c for c=0..7; out = v @ output_core.
// ---------------------------------------------------------------------------
__global__ __launch_bounds__(256) void combine(const float* __restrict__ P,
                                               const float* __restrict__ alpha,
                                               const float* __restrict__ oc,
                                               float* __restrict__ out)
{
    const int b = (int)blockIdx.x;
    const int tid = (int)threadIdx.x, j = tid & 63, q = tid >> 6;   // q = 0..3
    __shared__ float vb[BOND];
    __shared__ float ps[4][BOND];
    if (tid < BOND) vb[tid] = alpha[tid];
    __syncthreads();
    for (int ch = 0; ch < NCH; ++ch) {
        const float* Pc = P + (size_t)(b * NCH + ch) * 4096;
        float s = 0.f;
        #pragma unroll
        for (int k = 0; k < 16; ++k) {
            int i = q * 16 + k;
            s = fmaf(vb[i], Pc[i * 64 + j], s);
        }
        ps[q][j] = s;
        __syncthreads();
        if (q == 0) vb[j] = (ps[0][j] + ps[1][j]) + (ps[2][j] + ps[3][j]);
        __syncthreads();
    }
    if (tid < NOUT) {
        float s = 0.f;
        #pragma unroll 8
        for (int i = 0; i < BOND; ++i) s = fmaf(vb[i], oc[i * NOUT + tid], s);
        out[b * NOUT + tid] = s;
    }
}

extern "C" void kernel_launch(void* const* d_in, const int* in_sizes, int n_in,
                              void* d_out, int out_size, void* d_ws, size_t ws_size,
                              hipStream_t stream)
{
    const float* x     = (const float*)d_in[0];  // (256, 512, 33) f32
    const float* core  = (const float*)d_in[1];  // (64, 33, 64) f32
    const float* alpha = (const float*)d_in[2];  // (64,) f32
    const float* oc    = (const float*)d_in[3];  // (64, 32) f32
    float* out = (float*)d_out;                  // (256, 32) f32

    // workspace: [cfrag f16: 262144 B][P f32: 256*8*4096*4 = 33554432 B]
    _Float16* cfrag = (_Float16*)d_ws;
    float*    P     = (float*)((char*)d_ws + 262144);

    pack_cfrag<<<dim3(256), dim3(64), 0, stream>>>(core, cfrag);
    chunk_prod<<<dim3(NCH, NB), dim3(512), 0, stream>>>(x, cfrag, P);
    combine<<<dim3(NB), dim3(256), 0, stream>>>(P, alpha, oc, out);
}

// Round 10
// 429.006 us; speedup vs baseline: 1.0193x; 1.0193x over previous
//
#include <hip/hip_runtime.h>

#define NB    256               // batch
#define NT    512               // time steps
#define NF    33                // features incl. flag channel
#define BOND  64
#define NOUT  32
#define TC    64                // chunk length
#define NCH   (NT / TC)         // 8 chunks per batch

typedef _Float16 f16x4 __attribute__((ext_vector_type(4)));
typedef _Float16 f16x8 __attribute__((ext_vector_type(8)));
typedef float    f32x4 __attribute__((ext_vector_type(4)));

#define MFMA16(a, b, c) __builtin_amdgcn_mfma_f32_16x16x32_f16((a), (b), (c), 0, 0, 0)

// ---------------------------------------------------------------------------
// Phase 0: pack core channels f=1..32 into f16 MFMA A-fragment order,
// COLUMN-MAJOR flatten n' = j*64 + i (verbatim rounds 4-6, HW-verified).
// ---------------------------------------------------------------------------
__global__ __launch_bounds__(64) void pack_cfrag(const float* __restrict__ core,
                                                 _Float16* __restrict__ cfrag)
{
    int tid = blockIdx.x * 64 + threadIdx.x;      // 0 .. 16383
    int nt = tid >> 6, l = tid & 63;
    int g = l >> 4, c = l & 15;
    int n = nt * 16 + c;
    int i = n & 63, j = n >> 6;                   // column-major flatten
    const float* src = core + (size_t)i * (NF * BOND) + (size_t)(1 + g * 8) * BOND + j;
    f16x8 v;
    #pragma unroll
    for (int m = 0; m < 8; ++m) v[m] = (_Float16)src[(size_t)m * BOND];
    *(f16x8*)(cfrag + (size_t)tid * 8) = v;
}

// ---------------------------------------------------------------------------
// Phase 1: wave-specialized (round-8/9 structure, bit-verified twice).
// SPILL FIX: no register cache of cfrag — formation loads each fragment from
// global (L2-resident) at point of use, round-6-style; formation body now
// needs ~30 VGPRs, so neither divergent path exceeds the allocation.
// Waves 0-3: chain, P rows 16w..16w+15 in regs, per-step self-stage.
// Waves 4-7: form next round's 8 M^T slices into the other Mb half.
// M^T layout: slice sl, buffer-row j (M col), logical col i stored at
//   i ^ ((j&7)<<3) ^ (sl<<3)   (row-key XOR + slice-key XOR, stride 4096 f16).
// Barriers: stage-sync + 8 matched round events.
// ---------------------------------------------------------------------------
__global__ __launch_bounds__(512, 1) void chunk_prod(const float* __restrict__ x,
                                                     const _Float16* __restrict__ cfrag,
                                                     float* __restrict__ Pout)
{
    __shared__ __align__(16) _Float16 Mb[2][8 * 4096];   // dbuf x 8 slices
    __shared__ __align__(16) _Float16 Pst[4][16 * 64];   // per-chain-wave stage
    __shared__ __align__(16) _Float16 Xl[TC * 32];
    __shared__ float x0l[TC];

    const int tid = (int)threadIdx.x;
    const int l = tid & 63, w = tid >> 6;         // 8 waves
    const int g = l >> 4, c = l & 15;
    const int ch = (int)blockIdx.x, b = (int)blockIdx.y;
    const int sw = (c & 7) << 3;

    // ---- stage x chunk ----
    const float* xb = x + (size_t)b * (NT * NF) + (size_t)(ch * TC) * NF;
    for (int idx = tid; idx < TC * NF; idx += 512) {
        int t = idx / NF, f = idx - t * NF;
        float v = xb[idx];
        if (f == 0) x0l[t] = v;
        else        Xl[t * 32 + (f - 1)] = (_Float16)v;
    }
    __syncthreads();                              // event 0

    if (w >= 4) {
        // ================= formation waves =================
        const int fw = w - 4;                     // 0..3, owns n-tiles fw*64..+63
        const int sl = c & 7, sx = sl << 3;       // slice = c&7 (cols c, c+8 dup)
        const _Float16* cf0 = cfrag + ((size_t)(fw * 64) * 64 + (size_t)l) * 8;

        #pragma unroll 1
        for (int gi = 0; gi < 8; ++gi) {          // group gi ready before round gi
            _Float16* Mg = Mb[gi & 1];
            f16x8 xa = *(const f16x8*)(Xl + (gi * 8 + sl) * 32 + 8 * g);
            float x0v = x0l[gi * 8 + sl];
            #pragma unroll 4
            for (int q = 0; q < 64; ++q) {
                int nt = fw * 64 + q;
                f16x8 ca = *(const f16x8*)(cf0 + (size_t)q * 512);  // L2-hot
                f32x4 z = {0.f, 0.f, 0.f, 0.f};
                f32x4 d = MFMA16(ca, xa, z);      // lane: M[i0..i0+3][j], slice sl
                int j  = nt >> 2;
                int i0 = ((nt & 3) << 4) + (g << 2);
                int dr = j - i0;                  // diag slot if 0..3
                f16x4 mv;
                mv[0] = (_Float16)((dr == 0) ? d[0] + x0v : d[0]);   // RNE
                mv[1] = (_Float16)((dr == 1) ? d[1] + x0v : d[1]);
                mv[2] = (_Float16)((dr == 2) ? d[2] + x0v : d[2]);
                mv[3] = (_Float16)((dr == 3) ? d[3] + x0v : d[3]);
                *(f16x4*)(&Mg[sl * 4096 + (j << 6) + (i0 ^ ((j & 7) << 3) ^ sx)]) = mv;
            }
            __syncthreads();                      // events 1..8
        }
    } else {
        // ================= chain waves =================
        _Float16* Pw = &Pst[w][0];                // private 16x64 stage
        f16x8 a0, a1;                             // P[16w+c][kh*32+8g+m]
        #pragma unroll
        for (int m = 0; m < 8; ++m) {             // P = I (exact in f16)
            a0[m] = (_Float16)(((16 * w + c) == (8 * g + m)) ? 1.f : 0.f);
            a1[m] = (_Float16)(((16 * w + c) == (32 + 8 * g + m)) ? 1.f : 0.f);
        }
        f32x4 q0, q1, q2, q3;
        #pragma unroll 1
        for (int r = 0; r < 8; ++r) {
            __syncthreads();                      // events 1..8 (round r gated)
            const _Float16* Mg = Mb[r & 1];
            #pragma unroll
            for (int s = 0; s < 8; ++s) {
                const _Float16* Ms = Mg + s * 4096;
                const int kx0 = (8 * g) ^ sw ^ (s << 3);
                const int kx1 = kx0 ^ 32;
                f16x8 b00 = *(const f16x8*)(Ms + (c)      * 64 + kx0);
                f16x8 b01 = *(const f16x8*)(Ms + (c)      * 64 + kx1);
                f16x8 b10 = *(const f16x8*)(Ms + (16 + c) * 64 + kx0);
                f16x8 b11 = *(const f16x8*)(Ms + (16 + c) * 64 + kx1);
                f16x8 b20 = *(const f16x8*)(Ms + (32 + c) * 64 + kx0);
                f16x8 b21 = *(const f16x8*)(Ms + (32 + c) * 64 + kx1);
                f16x8 b30 = *(const f16x8*)(Ms + (48 + c) * 64 + kx0);
                f16x8 b31 = *(const f16x8*)(Ms + (48 + c) * 64 + kx1);
                f32x4 z = {0.f, 0.f, 0.f, 0.f};
                // swapped slots (round-6 verified): lane holds P'[16w+c][jb*16+4g+e]
                q0 = MFMA16(b00, a0, z); q0 = MFMA16(b01, a1, q0);
                q1 = MFMA16(b10, a0, z); q1 = MFMA16(b11, a1, q1);
                q2 = MFMA16(b20, a0, z); q2 = MFMA16(b21, a1, q2);
                q3 = MFMA16(b30, a0, z); q3 = MFMA16(b31, a1, q3);
                if (!(r == 7 && s == 7)) {
                    f16x4 h0, h1, h2, h3;         // RNE, as round 6
                    h0[0]=(_Float16)q0[0]; h0[1]=(_Float16)q0[1]; h0[2]=(_Float16)q0[2]; h0[3]=(_Float16)q0[3];
                    h1[0]=(_Float16)q1[0]; h1[1]=(_Float16)q1[1]; h1[2]=(_Float16)q1[2]; h1[3]=(_Float16)q1[3];
                    h2[0]=(_Float16)q2[0]; h2[1]=(_Float16)q2[1]; h2[2]=(_Float16)q2[2]; h2[3]=(_Float16)q2[3];
                    h3[0]=(_Float16)q3[0]; h3[1]=(_Float16)q3[1]; h3[2]=(_Float16)q3[2]; h3[3]=(_Float16)q3[3];
                    const int wc = (4 * g) ^ sw;  // row-key XOR store (row = c)
                    *(f16x4*)(Pw + c * 64 + wc)        = h0;
                    *(f16x4*)(Pw + c * 64 + (wc ^ 16)) = h1;
                    *(f16x4*)(Pw + c * 64 + (wc ^ 32)) = h2;
                    *(f16x4*)(Pw + c * 64 + (wc ^ 48)) = h3;
                    a0 = *(const f16x8*)(Pw + c * 64 + ((8 * g) ^ sw));
                    a1 = *(const f16x8*)(Pw + c * 64 + ((32 + 8 * g) ^ sw));
                }
            }
        }
        // final chunk product in f32 (pre-rounding), rows 16w+c
        float* Po = Pout + (size_t)(b * NCH + ch) * 4096;
        const int prow = 16 * w + c;
        *(f32x4*)(Po + prow * 64 +  0 + 4 * g) = q0;
        *(f32x4*)(Po + prow * 64 + 16 + 4 * g) = q1;
        *(f32x4*)(Po + prow * 64 + 32 + 4 * g) = q2;
        *(f32x4*)(Po + prow * 64 + 48 + 4 * g) = q3;
    }
}

// ---------------------------------------------------------------------------
// Phase 2: per batch, v = alpha; v = v @ P_c for c=0..7; out = v @ output_core.
// ---------------------------------------------------------------------------
__global__ __launch_bounds__(256) void combine(const float* __restrict__ P,
                                               const float* __restrict__ alpha,
                                               const float* __restrict__ oc,
                                               float* __restrict__ out)
{
    const int b = (int)blockIdx.x;
    const int tid = (int)threadIdx.x, j = tid & 63, q = tid >> 6;   // q = 0..3
    __shared__ float vb[BOND];
    __shared__ float ps[4][BOND];
    if (tid < BOND) vb[tid] = alpha[tid];
    __syncthreads();
    for (int ch = 0; ch < NCH; ++ch) {
        const float* Pc = P + (size_t)(b * NCH + ch) * 4096;
        float s = 0.f;
        #pragma unroll
        for (int k = 0; k < 16; ++k) {
            int i = q * 16 + k;
            s = fmaf(vb[i], Pc[i * 64 + j], s);
        }
        ps[q][j] = s;
        __syncthreads();
        if (q == 0) vb[j] = (ps[0][j] + ps[1][j]) + (ps[2][j] + ps[3][j]);
        __syncthreads();
    }
    if (tid < NOUT) {
        float s = 0.f;
        #pragma unroll 8
        for (int i = 0; i < BOND; ++i) s = fmaf(vb[i], oc[i * NOUT + tid], s);
        out[b * NOUT + tid] = s;
    }
}

extern "C" void kernel_launch(void* const* d_in, const int* in_sizes, int n_in,
                              void* d_out, int out_size, void* d_ws, size_t ws_size,
                              hipStream_t stream)
{
    const float* x     = (const float*)d_in[0];  // (256, 512, 33) f32
    const float* core  = (const float*)d_in[1];  // (64, 33, 64) f32
    const float* alpha = (const float*)d_in[2];  // (64,) f32
    const float* oc    = (const float*)d_in[3];  // (64, 32) f32
    float* out = (float*)d_out;                  // (256, 32) f32

    // workspace: [cfrag f16: 262144 B][P f32: 256*8*4096*4 = 33554432 B]
    _Float16* cfrag = (_Float16*)d_ws;
    float*    P     = (float*)((char*)d_ws + 262144);

    pack_cfrag<<<dim3(256), dim3(64), 0, stream>>>(core, cfrag);
    chunk_prod<<<dim3(NCH, NB), dim3(512), 0, stream>>>(x, cfrag, P);
    combine<<<dim3(NB), dim3(256), 0, stream>>>(P, alpha, oc, out);
}

// Round 11
// 350.019 us; speedup vs baseline: 1.2493x; 1.2257x over previous
//
#include <hip/hip_runtime.h>

#define NB    256               // batch
#define NT    512               // time steps
#define NF    33                // features incl. flag channel
#define BOND  64
#define NOUT  32
#define TC    64                // chunk length
#define NCH   (NT / TC)         // 8 chunks per batch

typedef _Float16 f16x4 __attribute__((ext_vector_type(4)));
typedef _Float16 f16x8 __attribute__((ext_vector_type(8)));
typedef float    f32x4 __attribute__((ext_vector_type(4)));

#define MFMA16(a, b, c) __builtin_amdgcn_mfma_f32_16x16x32_f16((a), (b), (c), 0, 0, 0)

// ---------------------------------------------------------------------------
// Phase 0: pack core channels f=1..32 into f16 MFMA A-fragment order,
// COLUMN-MAJOR flatten n' = j*64 + i (verbatim rounds 4-10, HW-verified).
// ---------------------------------------------------------------------------
__global__ __launch_bounds__(64) void pack_cfrag(const float* __restrict__ core,
                                                 _Float16* __restrict__ cfrag)
{
    int tid = blockIdx.x * 64 + threadIdx.x;      // 0 .. 16383
    int nt = tid >> 6, l = tid & 63;
    int g = l >> 4, c = l & 15;
    int n = nt * 16 + c;
    int i = n & 63, j = n >> 6;                   // column-major flatten
    const float* src = core + (size_t)i * (NF * BOND) + (size_t)(1 + g * 8) * BOND + j;
    f16x8 v;
    #pragma unroll
    for (int m = 0; m < 8; ++m) v[m] = (_Float16)src[(size_t)m * BOND];
    *(f16x8*)(cfrag + (size_t)tid * 8) = v;
}

// ---------------------------------------------------------------------------
// Phase 1: round-6 structure (all-wave formation + chain, bit-verified) on an
// LDS DIET for 2 blocks/CU (78080 B):
//  - M: 8 slices/group (8 groups), round-8 verified slice-XOR layout, 64 KB.
//  - P: single in-place 8 KB buffer; per step {bar; reads; bar; mfma+write}
//    (A-frags read full rows, written by the wave pair -> read-barrier).
//  - Xl/x0l as before (4.25 KB).
// Values and rounding order identical to round 6 => absmax must match exactly.
// ---------------------------------------------------------------------------
__global__ __launch_bounds__(512, 1) void chunk_prod(const float* __restrict__ x,
                                                     const _Float16* __restrict__ cfrag,
                                                     float* __restrict__ Pout)
{
    __shared__ __align__(16) _Float16 Mb[8 * 4096];   // 64 KB, slice-XOR
    __shared__ __align__(16) _Float16 PB[64 * 64];    // 8 KB, in-place P
    __shared__ __align__(16) _Float16 Xl[TC * 32];    // 4 KB
    __shared__ float x0l[TC];                         // 256 B

    const int tid = (int)threadIdx.x;
    const int l = tid & 63, w = tid >> 6;         // 8 waves
    const int g = l >> 4, c = l & 15;
    const int ch = (int)blockIdx.x, b = (int)blockIdx.y;
    const int sw = (c & 7) << 3;

    // ---- stage x chunk (round-6 verbatim) ----
    const float* xb = x + (size_t)b * (NT * NF) + (size_t)(ch * TC) * NF;
    for (int idx = tid; idx < TC * NF; idx += 512) {
        int t = idx / NF, f = idx - t * NF;
        float v = xb[idx];
        if (f == 0) x0l[t] = v;
        else        Xl[t * 32 + (f - 1)] = (_Float16)v;
    }
    // ---- P = I (row-major, swizzled; round-6 verbatim, single buffer) ----
    for (int idx = tid; idx < 4096; idx += 512) {
        int row = idx >> 6, col = idx & 63;
        PB[row * 64 + (col ^ ((row & 7) << 3))] = (row == col) ? (_Float16)1.f : (_Float16)0.f;
    }
    __syncthreads();                              // stage barrier

    const int rb = (w >> 1) << 4;                 // wave's P row block: 0/16/32/48
    const int cb = (w & 1) << 5;                  // wave's P col block: 0/32
    const int arow = rb + c;
    const int sl = c & 7, sx = sl << 3;           // formation slice (cols c,c+8 dup)
    const _Float16* cf0 = cfrag + ((size_t)(w * 32) * 64 + (size_t)l) * 8;

    #pragma unroll 1
    for (int gi = 0; gi < 8; ++gi) {
        // ==== formation: 8 M^T slices, t = gi*8 + sl (round-8 verified layout) ====
        f16x8 xa  = *(const f16x8*)(Xl + (gi * 8 + sl) * 32 + 8 * g);
        float x0v = x0l[gi * 8 + sl];
        #pragma unroll 4
        for (int q = 0; q < 32; ++q) {
            int nt = w * 32 + q;
            f16x8 ca = *(const f16x8*)(cf0 + (size_t)q * 512);  // L2-hot
            f32x4 z = {0.f, 0.f, 0.f, 0.f};
            f32x4 d = MFMA16(ca, xa, z);          // lane: M[i0..i0+3][j], slice sl
            int j  = nt >> 2;
            int i0 = ((nt & 3) << 4) + (g << 2);
            int dr = j - i0;                      // diag slot if 0..3
            f16x4 mv;
            mv[0] = (_Float16)((dr == 0) ? d[0] + x0v : d[0]);   // RNE
            mv[1] = (_Float16)((dr == 1) ? d[1] + x0v : d[1]);
            mv[2] = (_Float16)((dr == 2) ? d[2] + x0v : d[2]);
            mv[3] = (_Float16)((dr == 3) ? d[3] + x0v : d[3]);
            *(f16x4*)(&Mb[sl * 4096 + (j << 6) + (i0 ^ ((j & 7) << 3) ^ sx)]) = mv;
        }
        __syncthreads();                          // M visible + prev P-writes visible

        // ==== chain: 8 steps, in-place P, round-6 verified addressing ====
        #pragma unroll
        for (int s = 0; s < 8; ++s) {
            const _Float16* Ms = Mb + s * 4096;
            const int kx0 = (8 * g) ^ sw ^ (s << 3);
            const int kx1 = kx0 ^ 32;
            // reads (A from P rows arow; B from M^T rows, slice-XOR key)
            f16x8 a0  = *(const f16x8*)(PB + arow * 64 + ((8 * g) ^ sw));
            f16x8 a1  = *(const f16x8*)(PB + arow * 64 + ((32 + 8 * g) ^ sw));
            f16x8 b00 = *(const f16x8*)(Ms + (cb + c) * 64      + kx0);
            f16x8 b01 = *(const f16x8*)(Ms + (cb + c) * 64      + kx1);
            f16x8 b10 = *(const f16x8*)(Ms + (cb + 16 + c) * 64 + kx0);
            f16x8 b11 = *(const f16x8*)(Ms + (cb + 16 + c) * 64 + kx1);
            __syncthreads();                      // all pair reads done before writes
            f32x4 acc0 = {0.f, 0.f, 0.f, 0.f}, acc1 = {0.f, 0.f, 0.f, 0.f};
            // swapped slots (round-6 verified): lane holds P'[arow][cb(+16)+4g..+3]
            acc0 = MFMA16(b00, a0, acc0);
            acc0 = MFMA16(b01, a1, acc0);
            acc1 = MFMA16(b10, a0, acc1);
            acc1 = MFMA16(b11, a1, acc1);

            if (gi == 7 && s == 7) {              // final chunk product in f32
                float* Po = Pout + (size_t)(b * NCH + ch) * 4096;
                *(f32x4*)(Po + arow * 64 + cb + 4 * g)      = acc0;
                *(f32x4*)(Po + arow * 64 + cb + 16 + 4 * g) = acc1;
            } else {
                f16x4 h0, h1;                     // RNE, as round 6
                h0[0] = (_Float16)acc0[0]; h0[1] = (_Float16)acc0[1];
                h0[2] = (_Float16)acc0[2]; h0[3] = (_Float16)acc0[3];
                h1[0] = (_Float16)acc1[0]; h1[1] = (_Float16)acc1[1];
                h1[2] = (_Float16)acc1[2]; h1[3] = (_Float16)acc1[3];
                const int wcol = (cb + 4 * g) ^ sw;
                *(f16x4*)(PB + arow * 64 + wcol)        = h0;
                *(f16x4*)(PB + arow * 64 + (wcol ^ 16)) = h1;
                if (s != 7) __syncthreads();      // writes visible for next step
                // s==7: next formation touches only Mb/Xl; its barrier covers P.
            }
        }
    }
}

// ---------------------------------------------------------------------------
// Phase 2: per batch, v = alpha; v = v @ P_c for c=0..7; out = v @ output_core.
// ---------------------------------------------------------------------------
__global__ __launch_bounds__(256) void combine(const float* __restrict__ P,
                                               const float* __restrict__ alpha,
                                               const float* __restrict__ oc,
                                               float* __restrict__ out)
{
    const int b = (int)blockIdx.x;
    const int tid = (int)threadIdx.x, j = tid & 63, q = tid >> 6;   // q = 0..3
    __shared__ float vb[BOND];
    __shared__ float ps[4][BOND];
    if (tid < BOND) vb[tid] = alpha[tid];
    __syncthreads();
    for (int ch = 0; ch < NCH; ++ch) {
        const float* Pc = P + (size_t)(b * NCH + ch) * 4096;
        float s = 0.f;
        #pragma unroll
        for (int k = 0; k < 16; ++k) {
            int i = q * 16 + k;
            s = fmaf(vb[i], Pc[i * 64 + j], s);
        }
        ps[q][j] = s;
        __syncthreads();
        if (q == 0) vb[j] = (ps[0][j] + ps[1][j]) + (ps[2][j] + ps[3][j]);
        __syncthreads();
    }
    if (tid < NOUT) {
        float s = 0.f;
        #pragma unroll 8
        for (int i = 0; i < BOND; ++i) s = fmaf(vb[i], oc[i * NOUT + tid], s);
        out[b * NOUT + tid] = s;
    }
}

extern "C" void kernel_launch(void* const* d_in, const int* in_sizes, int n_in,
                              void* d_out, int out_size, void* d_ws, size_t ws_size,
                              hipStream_t stream)
{
    const float* x     = (const float*)d_in[0];  // (256, 512, 33) f32
    const float* core  = (const float*)d_in[1];  // (64, 33, 64) f32
    const float* alpha = (const float*)d_in[2];  // (64,) f32
    const float* oc    = (const float*)d_in[3];  // (64, 32) f32
    float* out = (float*)d_out;                  // (256, 32) f32

    // workspace: [cfrag f16: 262144 B][P f32: 256*8*4096*4 = 33554432 B]
    _Float16* cfrag = (_Float16*)d_ws;
    float*    P     = (float*)((char*)d_ws + 262144);

    pack_cfrag<<<dim3(256), dim3(64), 0, stream>>>(core, cfrag);
    chunk_prod<<<dim3(NCH, NB), dim3(512), 0, stream>>>(x, cfrag, P);
    combine<<<dim3(NB), dim3(256), 0, stream>>>(P, alpha, oc, out);
}

// Round 12
// 296.310 us; speedup vs baseline: 1.4758x; 1.1813x over previous
//
#include <hip/hip_runtime.h>

#define NB    256               // batch
#define NT    512               // time steps
#define NF    33                // features incl. flag channel
#define BOND  64
#define NOUT  32
#define TC    64                // chunk length
#define NCH   (NT / TC)         // 8 chunks per batch
#define MSTR  4104              // f16 stride per staged M^T slice (4096 + 8 -> bank skew)

typedef _Float16 f16x4 __attribute__((ext_vector_type(4)));
typedef _Float16 f16x8 __attribute__((ext_vector_type(8)));
typedef float    f32x4 __attribute__((ext_vector_type(4)));

#define MFMA16(a, b, c) __builtin_amdgcn_mfma_f32_16x16x32_f16((a), (b), (c), 0, 0, 0)

// ---------------------------------------------------------------------------
// Phase 0: pack core channels f=1..32 into f16 MFMA A-fragment order,
// COLUMN-MAJOR flatten n' = j*64 + i (verbatim rounds 4-11, HW-verified).
// ---------------------------------------------------------------------------
__global__ __launch_bounds__(64) void pack_cfrag(const float* __restrict__ core,
                                                 _Float16* __restrict__ cfrag)
{
    int tid = blockIdx.x * 64 + threadIdx.x;      // 0 .. 16383
    int nt = tid >> 6, l = tid & 63;
    int g = l >> 4, c = l & 15;
    int n = nt * 16 + c;
    int i = n & 63, j = n >> 6;                   // column-major flatten
    const float* src = core + (size_t)i * (NF * BOND) + (size_t)(1 + g * 8) * BOND + j;
    f16x8 v;
    #pragma unroll
    for (int m = 0; m < 8; ++m) v[m] = (_Float16)src[(size_t)m * BOND];
    *(f16x8*)(cfrag + (size_t)tid * 8) = v;
}

// ---------------------------------------------------------------------------
// Phase 1: round-6 structure (bit-verified, 195us) + B-fragment software
// prefetch: M^T is immutable within each fr, so step s issues step s+1's four
// B-reads BEFORE the barrier — they complete at the barrier's lgkm drain and
// the post-barrier critical path is only the two A-reads (P) -> MFMA.
// Values, layouts, rounding order identical to round 6.
// ---------------------------------------------------------------------------
__global__ __launch_bounds__(512, 1) void chunk_prod(const float* __restrict__ x,
                                                     const _Float16* __restrict__ cfrag,
                                                     float* __restrict__ Pout)
{
    __shared__ __align__(16) _Float16 PB[2][64 * 64];
    __shared__ __align__(16) _Float16 Mb[16 * MSTR];
    __shared__ __align__(16) _Float16 Xl[TC][32];
    __shared__ float x0l[TC];

    const int tid = (int)threadIdx.x;
    const int l = tid & 63, w = tid >> 6;         // 8 waves
    const int g = l >> 4, c = l & 15;
    const int ch = (int)blockIdx.x, b = (int)blockIdx.y;

    // ---- stage x chunk ----
    const float* xb = x + (size_t)b * (NT * NF) + (size_t)(ch * TC) * NF;
    for (int idx = tid; idx < TC * NF; idx += 512) {
        int t = idx / NF, f = idx - t * NF;
        float v = xb[idx];
        if (f == 0) x0l[t] = v;
        else        Xl[t][f - 1] = (_Float16)v;
    }
    // ---- P = I (row-major, swizzled) ----
    for (int idx = tid; idx < 4096; idx += 512) {
        int row = idx >> 6, col = idx & 63;
        PB[0][row * 64 + (col ^ ((row & 7) << 3))] = (row == col) ? (_Float16)1.f : (_Float16)0.f;
    }
    __syncthreads();

    const int sw = (c & 7) << 3;                  // row-XOR for all chain reads
    const int rb = (w >> 1) << 4;                 // wave's P row block: 0/16/32/48
    const int cb = (w & 1) << 5;                  // wave's P col block: 0/32
    const int arow = rb + c;
    const int wcol = (cb + 4 * g) ^ sw;           // P' write col base (row = arow)
    const int bo0 = (cb + c) * 64      + ((g * 8)      ^ sw);
    const int bo1 = (cb + c) * 64      + ((32 + g * 8) ^ sw);
    const int bo2 = (cb + 16 + c) * 64 + ((g * 8)      ^ sw);
    const int bo3 = (cb + 16 + c) * 64 + ((32 + g * 8) ^ sw);
    const _Float16* cf0 = cfrag + ((size_t)(w * 32) * 64 + (size_t)l) * 8;

    int pcur = 0;
    #pragma unroll 1
    for (int fr = 0; fr < 4; ++fr) {
        // ======== formation: M^T slices for t' = fr*16 + c (round-6 verbatim) ====
        f16x8 xa  = *(const f16x8*)&Xl[fr * 16 + c][g * 8];
        float x0v = x0l[fr * 16 + c];
        #pragma unroll 4
        for (int q = 0; q < 32; ++q) {
            int nt = w * 32 + q;
            f16x8 ca = *(const f16x8*)(cf0 + (size_t)q * 512);  // L2-hot
            f32x4 z = {0.f, 0.f, 0.f, 0.f};
            f32x4 d = MFMA16(ca, xa, z);
            int j  = nt >> 2;
            int i0 = ((nt & 3) << 4) + (g << 2);
            int dr = j - i0;                      // diag slot if 0..3
            f16x4 mv;
            mv[0] = (_Float16)((dr == 0) ? d[0] + x0v : d[0]);   // RNE
            mv[1] = (_Float16)((dr == 1) ? d[1] + x0v : d[1]);
            mv[2] = (_Float16)((dr == 2) ? d[2] + x0v : d[2]);
            mv[3] = (_Float16)((dr == 3) ? d[3] + x0v : d[3]);
            *(f16x4*)(&Mb[c * MSTR + (j << 6) + (i0 ^ ((j & 7) << 3))]) = mv;
        }
        __syncthreads();

        // ======== chain 16 steps with B-prefetch ========
        f16x8 p00 = *(const f16x8*)(Mb + bo0);    // B(0), issued post-formation-bar
        f16x8 p01 = *(const f16x8*)(Mb + bo1);
        f16x8 p10 = *(const f16x8*)(Mb + bo2);
        f16x8 p11 = *(const f16x8*)(Mb + bo3);
        #pragma unroll
        for (int s = 0; s < 16; ++s) {
            const _Float16* Ps = &PB[pcur][0];
            f16x8 a0 = *(const f16x8*)&Ps[arow * 64 + ((g * 8)      ^ sw)];
            f16x8 a1 = *(const f16x8*)&Ps[arow * 64 + ((32 + g * 8) ^ sw)];
            f16x8 b00 = p00, b01 = p01, b10 = p10, b11 = p11;
            if (s < 15) {                         // prefetch B(s+1): Mb immutable this fr
                const _Float16* Mn = Mb + (s + 1) * MSTR;
                p00 = *(const f16x8*)(Mn + bo0);
                p01 = *(const f16x8*)(Mn + bo1);
                p10 = *(const f16x8*)(Mn + bo2);
                p11 = *(const f16x8*)(Mn + bo3);
            }
            f32x4 acc0 = {0.f, 0.f, 0.f, 0.f}, acc1 = {0.f, 0.f, 0.f, 0.f};
            // swapped slots (round-6 verified): lane holds P'[arow][cb(+16)+4g..+3]
            acc0 = MFMA16(b00, a0, acc0);
            acc0 = MFMA16(b01, a1, acc0);
            acc1 = MFMA16(b10, a0, acc1);
            acc1 = MFMA16(b11, a1, acc1);

            if (fr == 3 && s == 15) {             // final chunk product in f32
                float* Po = Pout + (size_t)(b * NCH + ch) * 4096;
                *(f32x4*)(Po + arow * 64 + cb + 4 * g)      = acc0;
                *(f32x4*)(Po + arow * 64 + cb + 16 + 4 * g) = acc1;
            } else {
                _Float16* Pn = &PB[pcur ^ 1][0];
                f16x4 h0, h1;                     // RNE, as round 6
                h0[0] = (_Float16)acc0[0]; h0[1] = (_Float16)acc0[1];
                h0[2] = (_Float16)acc0[2]; h0[3] = (_Float16)acc0[3];
                h1[0] = (_Float16)acc1[0]; h1[1] = (_Float16)acc1[1];
                h1[2] = (_Float16)acc1[2]; h1[3] = (_Float16)acc1[3];
                *(f16x4*)(Pn + arow * 64 + wcol)        = h0;
                *(f16x4*)(Pn + arow * 64 + (wcol ^ 16)) = h1;
            }
            __syncthreads();
            pcur ^= 1;
        }
    }
}

// ---------------------------------------------------------------------------
// Phase 2: per batch, v = alpha; v = v @ P_c for c=0..7; out = v @ output_core.
// ---------------------------------------------------------------------------
__global__ __launch_bounds__(256) void combine(const float* __restrict__ P,
                                               const float* __restrict__ alpha,
                                               const float* __restrict__ oc,
                                               float* __restrict__ out)
{
    const int b = (int)blockIdx.x;
    const int tid = (int)threadIdx.x, j = tid & 63, q = tid >> 6;   // q = 0..3
    __shared__ float vb[BOND];
    __shared__ float ps[4][BOND];
    if (tid < BOND) vb[tid] = alpha[tid];
    __syncthreads();
    for (int ch = 0; ch < NCH; ++ch) {
        const float* Pc = P + (size_t)(b * NCH + ch) * 4096;
        float s = 0.f;
        #pragma unroll
        for (int k = 0; k < 16; ++k) {
            int i = q * 16 + k;
            s = fmaf(vb[i], Pc[i * 64 + j], s);
        }
        ps[q][j] = s;
        __syncthreads();
        if (q == 0) vb[j] = (ps[0][j] + ps[1][j]) + (ps[2][j] + ps[3][j]);
        __syncthreads();
    }
    if (tid < NOUT) {
        float s = 0.f;
        #pragma unroll 8
        for (int i = 0; i < BOND; ++i) s = fmaf(vb[i], oc[i * NOUT + tid], s);
        out[b * NOUT + tid] = s;
    }
}

extern "C" void kernel_launch(void* const* d_in, const int* in_sizes, int n_in,
                              void* d_out, int out_size, void* d_ws, size_t ws_size,
                              hipStream_t stream)
{
    const float* x     = (const float*)d_in[0];  // (256, 512, 33) f32
    const float* core  = (const float*)d_in[1];  // (64, 33, 64) f32
    const float* alpha = (const float*)d_in[2];  // (64,) f32
    const float* oc    = (const float*)d_in[3];  // (64, 32) f32
    float* out = (float*)d_out;                  // (256, 32) f32

    // workspace: [cfrag f16: 262144 B][P f32: 256*8*4096*4 = 33554432 B]
    _Float16* cfrag = (_Float16*)d_ws;
    float*    P     = (float*)((char*)d_ws + 262144);

    pack_cfrag<<<dim3(256), dim3(64), 0, stream>>>(core, cfrag);
    chunk_prod<<<dim3(NCH, NB), dim3(512), 0, stream>>>(x, cfrag, P);
    combine<<<dim3(NB), dim3(256), 0, stream>>>(P, alpha, oc, out);
}

// Round 13
// 240.819 us; speedup vs baseline: 1.8158x; 1.2304x over previous
//
#include <hip/hip_runtime.h>

#define NB    256               // batch
#define NT    512               // time steps
#define NF    33                // features incl. flag channel
#define BOND  64
#define NOUT  32
#define TC    64                // chunk length
#define NCH   (NT / TC)         // 8 chunks per batch
#define MSTR  4104              // f16 stride per staged M^T slice (4096 + 8 -> bank skew)

typedef _Float16 f16x4 __attribute__((ext_vector_type(4)));
typedef _Float16 f16x8 __attribute__((ext_vector_type(8)));
typedef float    f32x4 __attribute__((ext_vector_type(4)));

#define MFMA16(a, b, c) __builtin_amdgcn_mfma_f32_16x16x32_f16((a), (b), (c), 0, 0, 0)

// ---------------------------------------------------------------------------
// Phase 0: pack core channels f=1..32 into f16 MFMA A-fragment order,
// COLUMN-MAJOR flatten n' = j*64 + i (verbatim rounds 4-12, HW-verified).
// ---------------------------------------------------------------------------
__global__ __launch_bounds__(64) void pack_cfrag(const float* __restrict__ core,
                                                 _Float16* __restrict__ cfrag)
{
    int tid = blockIdx.x * 64 + threadIdx.x;      // 0 .. 16383
    int nt = tid >> 6, l = tid & 63;
    int g = l >> 4, c = l & 15;
    int n = nt * 16 + c;
    int i = n & 63, j = n >> 6;                   // column-major flatten
    const float* src = core + (size_t)i * (NF * BOND) + (size_t)(1 + g * 8) * BOND + j;
    f16x8 v;
    #pragma unroll
    for (int m = 0; m < 8; ++m) v[m] = (_Float16)src[(size_t)m * BOND];
    *(f16x8*)(cfrag + (size_t)tid * 8) = v;
}

// ---------------------------------------------------------------------------
// Phase 1: ROUND-6 VERBATIM (formation: creg + FULL unroll — compile-time
// diag-select and addresses; chain: swapped-slot MFMA, vector P' writes)
// + ONLY change: chain B-fragment prefetch. M^T (Mb) is immutable within an
// fr, so step s issues step s+1's four B-reads before its MFMAs; post-barrier
// critical path becomes the two A-reads only. pf[2][4] parity-indexed,
// compile-time under unroll (no copies). Bit-identical numerics to round 6.
// ---------------------------------------------------------------------------
__global__ __launch_bounds__(512, 1) void chunk_prod(const float* __restrict__ x,
                                                     const _Float16* __restrict__ cfrag,
                                                     float* __restrict__ Pout)
{
    __shared__ __align__(16) _Float16 PB[2][64 * 64];
    __shared__ __align__(16) _Float16 Mb[16 * MSTR];
    __shared__ __align__(16) _Float16 Xl[TC][32];
    __shared__ float x0l[TC];

    const int tid = (int)threadIdx.x;
    const int l = tid & 63, w = tid >> 6;         // 8 waves
    const int g = l >> 4, c = l & 15;
    const int ch = (int)blockIdx.x, b = (int)blockIdx.y;

    // ---- stage x chunk ----
    const float* xb = x + (size_t)b * (NT * NF) + (size_t)(ch * TC) * NF;
    for (int idx = tid; idx < TC * NF; idx += 512) {
        int t = idx / NF, f = idx - t * NF;
        float v = xb[idx];
        if (f == 0) x0l[t] = v;
        else        Xl[t][f - 1] = (_Float16)v;
    }
    // ---- P = I (row-major, swizzled) ----
    for (int idx = tid; idx < 4096; idx += 512) {
        int row = idx >> 6, col = idx & 63;
        PB[0][row * 64 + (col ^ ((row & 7) << 3))] = (row == col) ? (_Float16)1.f : (_Float16)0.f;
    }

    // ---- cache this wave's 32 cfrag tiles in registers (round-6 verbatim) ----
    f16x8 creg[32];
    {
        const _Float16* cf = cfrag + (size_t)w * 16384 + (size_t)l * 8;
        #pragma unroll
        for (int q = 0; q < 32; ++q) creg[q] = *(const f16x8*)(cf + (size_t)q * 512);
    }
    __syncthreads();

    const int sw = (c & 7) << 3;                  // row-XOR for all chain reads
    const int rb = (w >> 1) << 4;                 // wave's P row block: 0/16/32/48
    const int cb = (w & 1) << 5;                  // wave's P col block: 0/32
    const int arow = rb + c;
    const int wcol = (cb + 4 * g) ^ sw;           // P' write col base (row = arow)
    const int bo0 = (cb + c) * 64      + ((g * 8)      ^ sw);
    const int bo1 = (cb + c) * 64      + ((32 + g * 8) ^ sw);
    const int bo2 = (cb + 16 + c) * 64 + ((g * 8)      ^ sw);
    const int bo3 = (cb + 16 + c) * 64 + ((32 + g * 8) ^ sw);

    int pcur = 0;
    #pragma unroll 1
    for (int fr = 0; fr < 4; ++fr) {
        // ======== formation: M^T slices for t' = fr*16 + c (round-6 verbatim) ====
        f16x8 xa  = *(const f16x8*)&Xl[fr * 16 + c][g * 8];
        float x0v = x0l[fr * 16 + c];
        #pragma unroll
        for (int q = 0; q < 32; ++q) {
            int nt = w * 32 + q;
            f32x4 zero = {0.f, 0.f, 0.f, 0.f};
            f32x4 d = MFMA16(creg[q], xa, zero);
            // lane holds M[i0..i0+3][j], i0 = (nt&3)*16 + g*4, j = nt>>2
            int j  = nt >> 2;
            int i0 = ((nt & 3) << 4) + (g << 2);
            int dr = j - i0;                      // diag slot if 0..3 (compile-time per q)
            f16x4 mv;
            mv[0] = (_Float16)((dr == 0) ? d[0] + x0v : d[0]);   // RNE
            mv[1] = (_Float16)((dr == 1) ? d[1] + x0v : d[1]);
            mv[2] = (_Float16)((dr == 2) ? d[2] + x0v : d[2]);
            mv[3] = (_Float16)((dr == 3) ? d[3] + x0v : d[3]);
            *(f16x4*)(&Mb[c * MSTR + (j << 6) + (i0 ^ ((j & 7) << 3))]) = mv;
        }
        __syncthreads();

        // ======== chain 16 steps: B-prefetch, swapped-slot MFMA ========
        f16x8 pf[2][4];                           // static parity-indexed sets
        pf[0][0] = *(const f16x8*)(Mb + bo0);     // B(0), post-formation-barrier
        pf[0][1] = *(const f16x8*)(Mb + bo1);
        pf[0][2] = *(const f16x8*)(Mb + bo2);
        pf[0][3] = *(const f16x8*)(Mb + bo3);
        #pragma unroll 4
        for (int s = 0; s < 16; ++s) {
            const int cu = s & 1, nx = cu ^ 1;    // compile-time per unrolled body
            const _Float16* Ps = &PB[pcur][0];
            f16x8 a0 = *(const f16x8*)&Ps[arow * 64 + ((g * 8)      ^ sw)];
            f16x8 a1 = *(const f16x8*)&Ps[arow * 64 + ((32 + g * 8) ^ sw)];
            if (s < 15) {                         // prefetch B(s+1): Mb immutable this fr
                const _Float16* Mn = Mb + (s + 1) * MSTR;
                pf[nx][0] = *(const f16x8*)(Mn + bo0);
                pf[nx][1] = *(const f16x8*)(Mn + bo1);
                pf[nx][2] = *(const f16x8*)(Mn + bo2);
                pf[nx][3] = *(const f16x8*)(Mn + bo3);
            }
            f32x4 acc0 = {0.f, 0.f, 0.f, 0.f}, acc1 = {0.f, 0.f, 0.f, 0.f};
            // swapped slots (round-6 verified): lane holds P'[arow][cb(+16)+4g..+3]
            acc0 = MFMA16(pf[cu][0], a0, acc0);
            acc0 = MFMA16(pf[cu][1], a1, acc0);
            acc1 = MFMA16(pf[cu][2], a0, acc1);
            acc1 = MFMA16(pf[cu][3], a1, acc1);

            if (fr == 3 && s == 15) {             // final chunk product in f32
                float* Po = Pout + (size_t)(b * NCH + ch) * 4096;
                *(f32x4*)(Po + arow * 64 + cb + 4 * g)      = acc0;
                *(f32x4*)(Po + arow * 64 + cb + 16 + 4 * g) = acc1;
            } else {
                _Float16* Pn = &PB[pcur ^ 1][0];
                f16x4 h0, h1;                     // RNE, as round 6
                h0[0] = (_Float16)acc0[0]; h0[1] = (_Float16)acc0[1];
                h0[2] = (_Float16)acc0[2]; h0[3] = (_Float16)acc0[3];
                h1[0] = (_Float16)acc1[0]; h1[1] = (_Float16)acc1[1];
                h1[2] = (_Float16)acc1[2]; h1[3] = (_Float16)acc1[3];
                *(f16x4*)(Pn + arow * 64 + wcol)        = h0;
                *(f16x4*)(Pn + arow * 64 + (wcol ^ 16)) = h1;
            }
            __syncthreads();
            pcur ^= 1;
        }
    }
}

// ---------------------------------------------------------------------------
// Phase 2: per batch, v = alpha; v = v @ P_c for c=0..7; out = v @ output_core.
// ---------------------------------------------------------------------------
__global__ __launch_bounds__(256) void combine(const float* __restrict__ P,
                                               const float* __restrict__ alpha,
                                               const float* __restrict__ oc,
                                               float* __restrict__ out)
{
    const int b = (int)blockIdx.x;
    const int tid = (int)threadIdx.x, j = tid & 63, q = tid >> 6;   // q = 0..3
    __shared__ float vb[BOND];
    __shared__ float ps[4][BOND];
    if (tid < BOND) vb[tid] = alpha[tid];
    __syncthreads();
    for (int ch = 0; ch < NCH; ++ch) {
        const float* Pc = P + (size_t)(b * NCH + ch) * 4096;
        float s = 0.f;
        #pragma unroll
        for (int k = 0; k < 16; ++k) {
            int i = q * 16 + k;
            s = fmaf(vb[i], Pc[i * 64 + j], s);
        }
        ps[q][j] = s;
        __syncthreads();
        if (q == 0) vb[j] = (ps[0][j] + ps[1][j]) + (ps[2][j] + ps[3][j]);
        __syncthreads();
    }
    if (tid < NOUT) {
        float s = 0.f;
        #pragma unroll 8
        for (int i = 0; i < BOND; ++i) s = fmaf(vb[i], oc[i * NOUT + tid], s);
        out[b * NOUT + tid] = s;
    }
}

extern "C" void kernel_launch(void* const* d_in, const int* in_sizes, int n_in,
                              void* d_out, int out_size, void* d_ws, size_t ws_size,
                              hipStream_t stream)
{
    const float* x     = (const float*)d_in[0];  // (256, 512, 33) f32
    const float* core  = (const float*)d_in[1];  // (64, 33, 64) f32
    const float* alpha = (const float*)d_in[2];  // (64,) f32
    const float* oc    = (const float*)d_in[3];  // (64, 32) f32
    float* out = (float*)d_out;                  // (256, 32) f32

    // workspace: [cfrag f16: 262144 B][P f32: 256*8*4096*4 = 33554432 B]
    _Float16* cfrag = (_Float16*)d_ws;
    float*    P     = (float*)((char*)d_ws + 262144);

    pack_cfrag<<<dim3(256), dim3(64), 0, stream>>>(core, cfrag);
    chunk_prod<<<dim3(NCH, NB), dim3(512), 0, stream>>>(x, cfrag, P);
    combine<<<dim3(NB), dim3(256), 0, stream>>>(P, alpha, oc, out);
}